// Round 1
// baseline (273.472 us; speedup 1.0000x reference)
//
#include <hip/hip_runtime.h>

#define AS1 __attribute__((address_space(1)))
#define AS3 __attribute__((address_space(3)))

typedef __attribute__((ext_vector_type(8))) short short8;
typedef __attribute__((ext_vector_type(4))) float floatx4;

// ---- bf16 helpers (RNE; inputs are finite, no NaN/Inf handling needed) ----
__device__ __forceinline__ short f2bf(float f) {
  union { float f; unsigned u; } v; v.f = f;
  return (short)((v.u + 0x7fffu + ((v.u >> 16) & 1u)) >> 16);
}
__device__ __forceinline__ float bf2f(short s) {
  union { unsigned u; float f; } v; v.u = ((unsigned)(unsigned short)s) << 16;
  return v.f;
}

// ---- async global->LDS, 16B per lane (wave-uniform LDS base + lane*16) ----
__device__ __forceinline__ void gload_lds16(const void* g, void* l) {
  __builtin_amdgcn_global_load_lds((const AS1 unsigned*)g, (AS3 unsigned*)l, 16, 0, 0);
}

// Stage a 128x64 bf16 tile (rows rowBase..+127, cols kBase..+63) of row-major G
// (leading dim `ld` elements) into contiguous 128x64 LDS. 256 threads / 4 waves.
// Chunk c (1KB) = rows 8c..8c+7; lane i -> row i/8, 16B-col i%8  => lds byte c*1024 + i*16.
__device__ __forceinline__ void stage128x64(const short* __restrict__ G, long rowBase, long ld,
                                            int kBase, short* lds, int lane, int wave) {
  const short* gb = G + rowBase * ld + (long)kBase + (long)(lane >> 3) * ld + (lane & 7) * 8;
#pragma unroll
  for (int j = 0; j < 4; ++j) {
    int c = wave * 4 + j;
    gload_lds16(gb + (long)c * 8 * ld, lds + c * 512);
  }
}

// One BK=64 step of 128x128 MFMA tile compute. Wave (wm,wn) owns a 64x64 C block.
// A-frag: A[m = lane&15][k = (lane>>4)*8 + j]; B-frag: B[n = lane&15][k likewise].
// C/D: row = (lane>>4)*4 + r (M), col = lane&15 (N).
__device__ __forceinline__ void mfma_step(const short* lA, const short* lB, floatx4 acc[4][4],
                                          int lane, int wm, int wn) {
#pragma unroll
  for (int kk = 0; kk < 64; kk += 32) {
    short8 a[4], b[4];
    int kq = kk + (lane >> 4) * 8;
#pragma unroll
    for (int i = 0; i < 4; ++i) {
      a[i] = *(const short8*)(lA + (wm * 64 + i * 16 + (lane & 15)) * 64 + kq);
      b[i] = *(const short8*)(lB + (wn * 64 + i * 16 + (lane & 15)) * 64 + kq);
    }
#pragma unroll
    for (int i = 0; i < 4; ++i)
#pragma unroll
      for (int j = 0; j < 4; ++j)
        acc[i][j] = __builtin_amdgcn_mfma_f32_16x16x32_bf16(a[i], b[j], acc[i][j], 0, 0, 0);
  }
}

// ---- stage 0: fp32 -> bf16 convert of X ----
__global__ void convert_x(const float* __restrict__ X, short* __restrict__ Xb, long n) {
  long stride = (long)gridDim.x * blockDim.x * 4;
  for (long i = ((long)blockIdx.x * blockDim.x + threadIdx.x) * 4; i < n; i += stride) {
    float4 v = *(const float4*)(X + i);
    short4 o;
    o.x = f2bf(v.x); o.y = f2bf(v.y); o.z = f2bf(v.z); o.w = f2bf(v.w);
    *(short4*)(Xb + i) = o;
  }
}

// ---- stage 0b: W [k][n] fp32 -> Wt [n][k] bf16 (3 matrices via blockIdx.z) ----
__global__ void transpose_w(const float* __restrict__ Wq, const float* __restrict__ Wk,
                            const float* __restrict__ Wv, short* __restrict__ Wt) {
  __shared__ float t[32][33];
  const float* W = blockIdx.z == 0 ? Wq : (blockIdx.z == 1 ? Wk : Wv);
  short* O = Wt + (long)blockIdx.z * 1024 * 1024;
  int x = blockIdx.x * 32 + threadIdx.x;   // n (read), k col on write side
  int y0 = blockIdx.y * 32;
  for (int j = threadIdx.y; j < 32; j += 8)
    t[j][threadIdx.x] = W[(long)(y0 + j) * 1024 + x];
  __syncthreads();
  int x2 = blockIdx.y * 32 + threadIdx.x;  // k
  int y2 = blockIdx.x * 32;                // n
  for (int j = threadIdx.y; j < 32; j += 8)
    O[(long)(y2 + j) * 1024 + x2] = f2bf(t[threadIdx.x][j]);
}

// ---- stage 1: Q/K/V = X @ W  (A = Xb [8192,1024], B = Wt [1024,1024] both k-contig) ----
// z=0 -> Q [8192,1024], z=1 -> K [8192,1024], z=2 -> Vt [b][d][s] (transposed for PV stage)
__global__ __launch_bounds__(256) void gemm_qkv(const short* __restrict__ Xb,
                                                const short* __restrict__ Wt,
                                                short* __restrict__ Q, short* __restrict__ K2,
                                                short* __restrict__ Vt) {
  __shared__ short lA[128 * 64], lB[128 * 64];
  const int lane = threadIdx.x & 63, wave = threadIdx.x >> 6;
  const int wm = wave >> 1, wn = wave & 1;
  const int z = blockIdx.z;
  const short* Bm = Wt + (long)z * 1024 * 1024;
  const long mBase = (long)blockIdx.x * 128;
  const long nBase = (long)blockIdx.y * 128;

  floatx4 acc[4][4];
  const floatx4 zero = {0.f, 0.f, 0.f, 0.f};
#pragma unroll
  for (int i = 0; i < 4; ++i)
#pragma unroll
    for (int j = 0; j < 4; ++j) acc[i][j] = zero;

  for (int kt = 0; kt < 16; ++kt) {
    stage128x64(Xb, mBase, 1024, kt * 64, lA, lane, wave);
    stage128x64(Bm, nBase, 1024, kt * 64, lB, lane, wave);
    __syncthreads();
    mfma_step(lA, lB, acc, lane, wm, wn);
    __syncthreads();
  }

  if (z < 2) {
    short* out = (z == 0) ? Q : K2;
#pragma unroll
    for (int i = 0; i < 4; ++i)
#pragma unroll
      for (int j = 0; j < 4; ++j) {
        int col = (int)nBase + wn * 64 + j * 16 + (lane & 15);
#pragma unroll
        for (int r = 0; r < 4; ++r) {
          long m = mBase + wm * 64 + i * 16 + (lane >> 4) * 4 + r;
          out[m * 1024 + col] = f2bf(acc[i][j][r]);
        }
      }
  } else {
#pragma unroll
    for (int i = 0; i < 4; ++i)
#pragma unroll
      for (int j = 0; j < 4; ++j) {
        int col = (int)nBase + wn * 64 + j * 16 + (lane & 15);  // d
#pragma unroll
        for (int r = 0; r < 4; ++r) {
          long m = mBase + wm * 64 + i * 16 + (lane >> 4) * 4 + r;  // global token
          long bb = m >> 11, s = m & 2047;
          Vt[(bb * 1024 + col) * 2048 + s] = f2bf(acc[i][j][r]);
        }
      }
  }
}

// ---- stage 2: E = exp(Q K^T / 32) on causal block pairs; row sums into l (atomics) ----
__global__ __launch_bounds__(256) void scores_exp(const short* __restrict__ Q,
                                                  const short* __restrict__ Kk,
                                                  short* __restrict__ E, float* __restrict__ l) {
  __shared__ short lA[128 * 64], lB[128 * 64];
  const int lane = threadIdx.x & 63, wave = threadIdx.x >> 6;
  const int wm = wave >> 1, wn = wave & 1;
  const int b = blockIdx.y;
  // decode (qt, kt) with kt <= qt from flat pair index
  int qt = 0, rem = blockIdx.x;
  while (rem > qt) { rem -= (qt + 1); ++qt; }
  const int kt = rem;

  const long rowQ = (long)b * 2048 + (long)qt * 128;
  const long rowK = (long)b * 2048 + (long)kt * 128;

  floatx4 acc[4][4];
  const floatx4 zero = {0.f, 0.f, 0.f, 0.f};
#pragma unroll
  for (int i = 0; i < 4; ++i)
#pragma unroll
    for (int j = 0; j < 4; ++j) acc[i][j] = zero;

  for (int it = 0; it < 16; ++it) {
    stage128x64(Q, rowQ, 1024, it * 64, lA, lane, wave);
    stage128x64(Kk, rowK, 1024, it * 64, lB, lane, wave);
    __syncthreads();
    mfma_step(lA, lB, acc, lane, wm, wn);
    __syncthreads();
  }

  short* Eb = E + (long)b * 2048 * 2048;
  float* lrow = l + (long)b * 2048;
#pragma unroll
  for (int i = 0; i < 4; ++i) {
#pragma unroll
    for (int r = 0; r < 4; ++r) {
      int ri = wm * 64 + i * 16 + (lane >> 4) * 4 + r;
      int qrow = qt * 128 + ri;
      float p = 0.f;
#pragma unroll
      for (int j = 0; j < 4; ++j) {
        int col = kt * 128 + wn * 64 + j * 16 + (lane & 15);
        float s = acc[i][j][r] * 0.03125f;  // 1/sqrt(1024)
        float e = (col <= qrow) ? __expf(s) : 0.0f;
        short eb = f2bf(e);
        Eb[(long)qrow * 2048 + col] = eb;
        p += bf2f(eb);  // sum what PV will actually read
      }
      // reduce across the 16 lanes sharing this row (cols)
      for (int m = 1; m < 16; m <<= 1) p += __shfl_xor(p, m, 64);
      if ((lane & 15) == 0) atomicAdd(&lrow[qrow], p);
    }
  }
}

// ---- stage 3: O = (E @ V) / l ; A = E[b] [2048,2048], B = Vt[b] [1024,2048] ----
__global__ __launch_bounds__(256) void pv_gemm(const short* __restrict__ E,
                                               const short* __restrict__ Vt,
                                               const float* __restrict__ l,
                                               float* __restrict__ out) {
  __shared__ short lA[128 * 64], lB[128 * 64];
  const int lane = threadIdx.x & 63, wave = threadIdx.x >> 6;
  const int wm = wave >> 1, wn = wave & 1;
  const int qt = blockIdx.x, dt = blockIdx.y, b = blockIdx.z;
  const short* Eb = E + (long)b * 2048 * 2048;
  const short* Vb = Vt + (long)b * 1024 * 2048;

  floatx4 acc[4][4];
  const floatx4 zero = {0.f, 0.f, 0.f, 0.f};
#pragma unroll
  for (int i = 0; i < 4; ++i)
#pragma unroll
    for (int j = 0; j < 4; ++j) acc[i][j] = zero;

  const int nIter = (qt + 1) * 2;  // causal: reduce over k = 0 .. (qt+1)*128
  for (int it = 0; it < nIter; ++it) {
    stage128x64(Eb, (long)qt * 128, 2048, it * 64, lA, lane, wave);
    stage128x64(Vb, (long)dt * 128, 2048, it * 64, lB, lane, wave);
    __syncthreads();
    mfma_step(lA, lB, acc, lane, wm, wn);
    __syncthreads();
  }

  const float* lrow = l + (long)b * 2048;
#pragma unroll
  for (int i = 0; i < 4; ++i) {
#pragma unroll
    for (int r = 0; r < 4; ++r) {
      int qrow = qt * 128 + wm * 64 + i * 16 + (lane >> 4) * 4 + r;
      float inv = 1.0f / lrow[qrow];
#pragma unroll
      for (int j = 0; j < 4; ++j) {
        int d = dt * 128 + wn * 64 + j * 16 + (lane & 15);
        out[((long)b * 2048 + qrow) * 1024 + d] = acc[i][j][r] * inv;
      }
    }
  }
}

extern "C" void kernel_launch(void* const* d_in, const int* in_sizes, int n_in,
                              void* d_out, int out_size, void* d_ws, size_t ws_size,
                              hipStream_t stream) {
  const float* X  = (const float*)d_in[0];
  const float* Wq = (const float*)d_in[1];
  const float* Wk = (const float*)d_in[2];
  const float* Wv = (const float*)d_in[3];

  char* ws = (char*)d_ws;
  // layout (bytes): Xb 16M | Wt 6M | Q 16M | K 16M | Vt 16M | E 32M | l 32K  (~102 MiB)
  short* Xb = (short*)(ws);
  short* Wt = (short*)(ws + 16777216L);
  short* Q  = (short*)(ws + 23068672L);
  short* K2 = (short*)(ws + 39845888L);
  short* Vt = (short*)(ws + 56623104L);
  short* E  = (short*)(ws + 73400320L);
  float* l  = (float*)(ws + 106954752L);

  hipMemsetAsync(l, 0, 4 * 2048 * sizeof(float), stream);
  convert_x<<<2048, 256, 0, stream>>>(X, Xb, 8192L * 1024);
  transpose_w<<<dim3(32, 32, 3), dim3(32, 8), 0, stream>>>(Wq, Wk, Wv, Wt);
  gemm_qkv<<<dim3(64, 8, 3), 256, 0, stream>>>(Xb, Wt, Q, K2, Vt);
  scores_exp<<<dim3(136, 4), 256, 0, stream>>>(Q, K2, E, l);
  pv_gemm<<<dim3(16, 8, 4), 256, 0, stream>>>(E, Vt, l, (float*)d_out);
}

// Round 2
// 272.294 us; speedup vs baseline: 1.0043x; 1.0043x over previous
//
#include <hip/hip_runtime.h>

#define AS1 __attribute__((address_space(1)))
#define AS3 __attribute__((address_space(3)))

typedef __attribute__((ext_vector_type(8))) short short8;
typedef __attribute__((ext_vector_type(4))) float floatx4;

// ---- bf16 helpers (RNE; inputs are finite, no NaN/Inf handling needed) ----
__device__ __forceinline__ short f2bf(float f) {
  union { float f; unsigned u; } v; v.f = f;
  return (short)((v.u + 0x7fffu + ((v.u >> 16) & 1u)) >> 16);
}
__device__ __forceinline__ float bf2f(short s) {
  union { unsigned u; float f; } v; v.u = ((unsigned)(unsigned short)s) << 16;
  return v.f;
}

// ---- async global->LDS, 16B per lane (wave-uniform LDS base + lane*16) ----
__device__ __forceinline__ void gload_lds16(const void* g, void* l) {
  __builtin_amdgcn_global_load_lds((const AS1 unsigned*)g, (AS3 unsigned*)l, 16, 0, 0);
}

// Stage a 128x64 bf16 tile (rows rowBase..+127, cols kBase..+63) of row-major G
// (leading dim `ld` elements) into contiguous 128x64 LDS. 256 threads / 4 waves.
__device__ __forceinline__ void stage128x64(const short* __restrict__ G, long rowBase, long ld,
                                            int kBase, short* lds, int lane, int wave) {
  const short* gb = G + rowBase * ld + (long)kBase + (long)(lane >> 3) * ld + (lane & 7) * 8;
#pragma unroll
  for (int j = 0; j < 4; ++j) {
    int c = wave * 4 + j;
    gload_lds16(gb + (long)c * 8 * ld, lds + c * 512);
  }
}

// One BK=64 step of 128x128 MFMA tile compute. Wave (wm,wn) owns a 64x64 C block.
__device__ __forceinline__ void mfma_step(const short* lA, const short* lB, floatx4 acc[4][4],
                                          int lane, int wm, int wn) {
#pragma unroll
  for (int kk = 0; kk < 64; kk += 32) {
    short8 a[4], b[4];
    int kq = kk + (lane >> 4) * 8;
#pragma unroll
    for (int i = 0; i < 4; ++i) {
      a[i] = *(const short8*)(lA + (wm * 64 + i * 16 + (lane & 15)) * 64 + kq);
      b[i] = *(const short8*)(lB + (wn * 64 + i * 16 + (lane & 15)) * 64 + kq);
    }
#pragma unroll
    for (int i = 0; i < 4; ++i)
#pragma unroll
      for (int j = 0; j < 4; ++j)
        acc[i][j] = __builtin_amdgcn_mfma_f32_16x16x32_bf16(a[i], b[j], acc[i][j], 0, 0, 0);
  }
}

// ---- stage 0: fp32 -> bf16 convert of X ----
__global__ void convert_x(const float* __restrict__ X, short* __restrict__ Xb, long n) {
  long stride = (long)gridDim.x * blockDim.x * 4;
  for (long i = ((long)blockIdx.x * blockDim.x + threadIdx.x) * 4; i < n; i += stride) {
    float4 v = *(const float4*)(X + i);
    short4 o;
    o.x = f2bf(v.x); o.y = f2bf(v.y); o.z = f2bf(v.z); o.w = f2bf(v.w);
    *(short4*)(Xb + i) = o;
  }
}

// ---- stage 0b: W [k][n] fp32 -> Wt [n][k] bf16 (3 matrices via blockIdx.z) ----
__global__ void transpose_w(const float* __restrict__ Wq, const float* __restrict__ Wk,
                            const float* __restrict__ Wv, short* __restrict__ Wt) {
  __shared__ float t[32][33];
  const float* W = blockIdx.z == 0 ? Wq : (blockIdx.z == 1 ? Wk : Wv);
  short* O = Wt + (long)blockIdx.z * 1024 * 1024;
  int x = blockIdx.x * 32 + threadIdx.x;
  int y0 = blockIdx.y * 32;
  for (int j = threadIdx.y; j < 32; j += 8)
    t[j][threadIdx.x] = W[(long)(y0 + j) * 1024 + x];
  __syncthreads();
  int x2 = blockIdx.y * 32 + threadIdx.x;
  int y2 = blockIdx.x * 32;
  for (int j = threadIdx.y; j < 32; j += 8)
    O[(long)(y2 + j) * 1024 + x2] = f2bf(t[threadIdx.x][j]);
}

// ---- stage 1: Q/K/V = X @ W ----
// z=0 -> Q [8192,1024], z=1 -> K [8192,1024], z=2 -> Vt [b][d][s]
__global__ __launch_bounds__(256) void gemm_qkv(const short* __restrict__ Xb,
                                                const short* __restrict__ Wt,
                                                short* __restrict__ Q, short* __restrict__ K2,
                                                short* __restrict__ Vt) {
  __shared__ short lA[128 * 64], lB[128 * 64];
  const int lane = threadIdx.x & 63, wave = threadIdx.x >> 6;
  const int wm = wave >> 1, wn = wave & 1;
  const int z = blockIdx.z;
  const short* Bm = Wt + (long)z * 1024 * 1024;
  const long mBase = (long)blockIdx.x * 128;
  const long nBase = (long)blockIdx.y * 128;

  floatx4 acc[4][4];
  const floatx4 zero = {0.f, 0.f, 0.f, 0.f};
#pragma unroll
  for (int i = 0; i < 4; ++i)
#pragma unroll
    for (int j = 0; j < 4; ++j) acc[i][j] = zero;

  for (int kt = 0; kt < 16; ++kt) {
    stage128x64(Xb, mBase, 1024, kt * 64, lA, lane, wave);
    stage128x64(Bm, nBase, 1024, kt * 64, lB, lane, wave);
    __syncthreads();
    mfma_step(lA, lB, acc, lane, wm, wn);
    __syncthreads();
  }

  if (z < 2) {
    short* out = (z == 0) ? Q : K2;
#pragma unroll
    for (int i = 0; i < 4; ++i)
#pragma unroll
      for (int j = 0; j < 4; ++j) {
        int col = (int)nBase + wn * 64 + j * 16 + (lane & 15);
#pragma unroll
        for (int r = 0; r < 4; ++r) {
          long m = mBase + wm * 64 + i * 16 + (lane >> 4) * 4 + r;
          out[m * 1024 + col] = f2bf(acc[i][j][r]);
        }
      }
  } else {
    // V transposed write: in Vt[b][d][s], the 4 r-values are s-contiguous -> short4 store
    const long bb = mBase >> 11;
    const int sBase = (int)(mBase & 2047);
#pragma unroll
    for (int i = 0; i < 4; ++i) {
      int s0 = sBase + wm * 64 + i * 16 + ((lane >> 4) << 2);
#pragma unroll
      for (int j = 0; j < 4; ++j) {
        int col = (int)nBase + wn * 64 + j * 16 + (lane & 15);
        short4 o;
        o.x = f2bf(acc[i][j][0]); o.y = f2bf(acc[i][j][1]);
        o.z = f2bf(acc[i][j][2]); o.w = f2bf(acc[i][j][3]);
        *(short4*)(Vt + ((bb * 1024 + col) * 2048 + s0)) = o;
      }
    }
  }
}

// ---- stage 2: E = exp(Q K^T / 32) on causal block pairs; row sums into l ----
__global__ __launch_bounds__(256) void scores_exp(const short* __restrict__ Q,
                                                  const short* __restrict__ Kk,
                                                  short* __restrict__ E, float* __restrict__ l) {
  __shared__ short lA[128 * 64], lB[128 * 64];
  const int lane = threadIdx.x & 63, wave = threadIdx.x >> 6;
  const int wm = wave >> 1, wn = wave & 1;
  const int b = blockIdx.y;
  int qt = 0, rem = blockIdx.x;
  while (rem > qt) { rem -= (qt + 1); ++qt; }
  const int kt = rem;

  const long rowQ = (long)b * 2048 + (long)qt * 128;
  const long rowK = (long)b * 2048 + (long)kt * 128;

  floatx4 acc[4][4];
  const floatx4 zero = {0.f, 0.f, 0.f, 0.f};
#pragma unroll
  for (int i = 0; i < 4; ++i)
#pragma unroll
    for (int j = 0; j < 4; ++j) acc[i][j] = zero;

  for (int it = 0; it < 16; ++it) {
    stage128x64(Q, rowQ, 1024, it * 64, lA, lane, wave);
    stage128x64(Kk, rowK, 1024, it * 64, lB, lane, wave);
    __syncthreads();
    mfma_step(lA, lB, acc, lane, wm, wn);
    __syncthreads();
  }

  short* Eb = E + (long)b * 2048 * 2048;
  float* lrow = l + (long)b * 2048;
#pragma unroll
  for (int i = 0; i < 4; ++i) {
#pragma unroll
    for (int r = 0; r < 4; ++r) {
      int ri = wm * 64 + i * 16 + (lane >> 4) * 4 + r;
      int qrow = qt * 128 + ri;
      float p = 0.f;
#pragma unroll
      for (int j = 0; j < 4; ++j) {
        int col = kt * 128 + wn * 64 + j * 16 + (lane & 15);
        float s = acc[i][j][r] * 0.03125f;  // 1/sqrt(1024)
        float e = (col <= qrow) ? __expf(s) : 0.0f;
        short eb = f2bf(e);
        Eb[(long)qrow * 2048 + col] = eb;
        p += bf2f(eb);
      }
      for (int m = 1; m < 16; m <<= 1) p += __shfl_xor(p, m, 64);
      if ((lane & 15) == 0) atomicAdd(&lrow[qrow], p);
    }
  }
}

// ---- stage 3: O = (E @ V) / l, statically load-balanced ----
// Block a handles qt = 15-a then qt = a: every block does exactly 34 k-iters.
__global__ __launch_bounds__(256) void pv_gemm(const short* __restrict__ E,
                                               const short* __restrict__ Vt,
                                               const float* __restrict__ l,
                                               float* __restrict__ out) {
  __shared__ short lA[128 * 64], lB[128 * 64];
  const int lane = threadIdx.x & 63, wave = threadIdx.x >> 6;
  const int wm = wave >> 1, wn = wave & 1;
  const int a = blockIdx.x, dt = blockIdx.y, b = blockIdx.z;
  const short* Eb = E + (long)b * 2048 * 2048;
  const short* Vb = Vt + (long)b * 1024 * 2048;
  const float* lrow = l + (long)b * 2048;
  const floatx4 zero = {0.f, 0.f, 0.f, 0.f};

#pragma unroll
  for (int phase = 0; phase < 2; ++phase) {
    const int qt = (phase == 0) ? (15 - a) : a;

    floatx4 acc[4][4];
#pragma unroll
    for (int i = 0; i < 4; ++i)
#pragma unroll
      for (int j = 0; j < 4; ++j) acc[i][j] = zero;

    const int nIter = (qt + 1) * 2;
    for (int it = 0; it < nIter; ++it) {
      stage128x64(Eb, (long)qt * 128, 2048, it * 64, lA, lane, wave);
      stage128x64(Vb, (long)dt * 128, 2048, it * 64, lB, lane, wave);
      __syncthreads();
      mfma_step(lA, lB, acc, lane, wm, wn);
      __syncthreads();
    }

#pragma unroll
    for (int i = 0; i < 4; ++i) {
#pragma unroll
      for (int r = 0; r < 4; ++r) {
        int qrow = qt * 128 + wm * 64 + i * 16 + (lane >> 4) * 4 + r;
        float inv = 1.0f / lrow[qrow];
#pragma unroll
        for (int j = 0; j < 4; ++j) {
          int d = dt * 128 + wn * 64 + j * 16 + (lane & 15);
          out[((long)b * 2048 + qrow) * 1024 + d] = acc[i][j][r] * inv;
        }
      }
    }
  }
}

extern "C" void kernel_launch(void* const* d_in, const int* in_sizes, int n_in,
                              void* d_out, int out_size, void* d_ws, size_t ws_size,
                              hipStream_t stream) {
  const float* X  = (const float*)d_in[0];
  const float* Wq = (const float*)d_in[1];
  const float* Wk = (const float*)d_in[2];
  const float* Wv = (const float*)d_in[3];

  char* ws = (char*)d_ws;
  // layout (bytes): Xb 16M | Wt 6M | Q 16M | K 16M | Vt 16M | E 32M | l 32K
  short* Xb = (short*)(ws);
  short* Wt = (short*)(ws + 16777216L);
  short* Q  = (short*)(ws + 23068672L);
  short* K2 = (short*)(ws + 39845888L);
  short* Vt = (short*)(ws + 56623104L);
  short* E  = (short*)(ws + 73400320L);
  float* l  = (float*)(ws + 106954752L);

  hipMemsetAsync(l, 0, 4 * 2048 * sizeof(float), stream);
  convert_x<<<2048, 256, 0, stream>>>(X, Xb, 8192L * 1024);
  transpose_w<<<dim3(32, 32, 3), dim3(32, 8), 0, stream>>>(Wq, Wk, Wv, Wt);
  gemm_qkv<<<dim3(64, 8, 3), 256, 0, stream>>>(Xb, Wt, Q, K2, Vt);
  scores_exp<<<dim3(136, 4), 256, 0, stream>>>(Q, K2, E, l);
  pv_gemm<<<dim3(8, 8, 4), 256, 0, stream>>>(E, Vt, l, (float*)d_out);
}

// Round 3
// 249.486 us; speedup vs baseline: 1.0961x; 1.0914x over previous
//
#include <hip/hip_runtime.h>

#define AS1 __attribute__((address_space(1)))
#define AS3 __attribute__((address_space(3)))

typedef __attribute__((ext_vector_type(8))) short short8;
typedef __attribute__((ext_vector_type(4))) float floatx4;

// ---- bf16 helpers (RNE; inputs are finite, no NaN/Inf handling needed) ----
__device__ __forceinline__ short f2bf(float f) {
  union { float f; unsigned u; } v; v.f = f;
  return (short)((v.u + 0x7fffu + ((v.u >> 16) & 1u)) >> 16);
}
__device__ __forceinline__ float bf2f(short s) {
  union { unsigned u; float f; } v; v.u = ((unsigned)(unsigned short)s) << 16;
  return v.f;
}

// ---- async global->LDS, 16B per lane (wave-uniform LDS base + lane*16) ----
__device__ __forceinline__ void gload_lds16(const void* g, void* l) {
  __builtin_amdgcn_global_load_lds((const AS1 unsigned*)g, (AS3 unsigned*)l, 16, 0, 0);
}

// Stage a 128x64 bf16 tile (rows rowBase..+127, cols kBase..+63) of row-major G
// (leading dim `ld` elements) into contiguous 128x64 LDS. 256 threads / 4 waves.
__device__ __forceinline__ void stage128x64(const short* __restrict__ G, long rowBase, long ld,
                                            int kBase, short* lds, int lane, int wave) {
  const short* gb = G + rowBase * ld + (long)kBase + (long)(lane >> 3) * ld + (lane & 7) * 8;
#pragma unroll
  for (int j = 0; j < 4; ++j) {
    int c = wave * 4 + j;
    gload_lds16(gb + (long)c * 8 * ld, lds + c * 512);
  }
}

// One BK=64 step of 128x128 MFMA tile compute. Wave (wm,wn) owns a 64x64 C block.
__device__ __forceinline__ void mfma_step(const short* lA, const short* lB, floatx4 acc[4][4],
                                          int lane, int wm, int wn) {
#pragma unroll
  for (int kk = 0; kk < 64; kk += 32) {
    short8 a[4], b[4];
    int kq = kk + (lane >> 4) * 8;
#pragma unroll
    for (int i = 0; i < 4; ++i) {
      a[i] = *(const short8*)(lA + (wm * 64 + i * 16 + (lane & 15)) * 64 + kq);
      b[i] = *(const short8*)(lB + (wn * 64 + i * 16 + (lane & 15)) * 64 + kq);
    }
#pragma unroll
    for (int i = 0; i < 4; ++i)
#pragma unroll
      for (int j = 0; j < 4; ++j)
        acc[i][j] = __builtin_amdgcn_mfma_f32_16x16x32_bf16(a[i], b[j], acc[i][j], 0, 0, 0);
  }
}

// ---- stage 0: fp32 -> bf16 convert of X ----
__global__ void convert_x(const float* __restrict__ X, short* __restrict__ Xb, long n) {
  long stride = (long)gridDim.x * blockDim.x * 4;
  for (long i = ((long)blockIdx.x * blockDim.x + threadIdx.x) * 4; i < n; i += stride) {
    float4 v = *(const float4*)(X + i);
    short4 o;
    o.x = f2bf(v.x); o.y = f2bf(v.y); o.z = f2bf(v.z); o.w = f2bf(v.w);
    *(short4*)(Xb + i) = o;
  }
}

// ---- stage 0b: W [k][n] fp32 -> Wt [n][k] bf16 (3 matrices via blockIdx.z) ----
__global__ void transpose_w(const float* __restrict__ Wq, const float* __restrict__ Wk,
                            const float* __restrict__ Wv, short* __restrict__ Wt) {
  __shared__ float t[32][33];
  const float* W = blockIdx.z == 0 ? Wq : (blockIdx.z == 1 ? Wk : Wv);
  short* O = Wt + (long)blockIdx.z * 1024 * 1024;
  int x = blockIdx.x * 32 + threadIdx.x;
  int y0 = blockIdx.y * 32;
  for (int j = threadIdx.y; j < 32; j += 8)
    t[j][threadIdx.x] = W[(long)(y0 + j) * 1024 + x];
  __syncthreads();
  int x2 = blockIdx.y * 32 + threadIdx.x;
  int y2 = blockIdx.x * 32;
  for (int j = threadIdx.y; j < 32; j += 8)
    O[(long)(y2 + j) * 1024 + x2] = f2bf(t[threadIdx.x][j]);
}

// ---- stage 1: Q/K/V = X @ W ----
// z=0 -> Q [8192,1024], z=1 -> K [8192,1024], z=2 -> Vt [b][d][s]
__global__ __launch_bounds__(256, 3) void gemm_qkv(const short* __restrict__ Xb,
                                                   const short* __restrict__ Wt,
                                                   short* __restrict__ Q, short* __restrict__ K2,
                                                   short* __restrict__ Vt) {
  __shared__ short lA[128 * 64], lB[128 * 64];
  const int lane = threadIdx.x & 63, wave = threadIdx.x >> 6;
  const int wm = wave >> 1, wn = wave & 1;
  const int z = blockIdx.z;
  const short* Bm = Wt + (long)z * 1024 * 1024;
  const long mBase = (long)blockIdx.x * 128;
  const long nBase = (long)blockIdx.y * 128;

  floatx4 acc[4][4];
  const floatx4 zero = {0.f, 0.f, 0.f, 0.f};
#pragma unroll
  for (int i = 0; i < 4; ++i)
#pragma unroll
    for (int j = 0; j < 4; ++j) acc[i][j] = zero;

  for (int kt = 0; kt < 16; ++kt) {
    stage128x64(Xb, mBase, 1024, kt * 64, lA, lane, wave);
    stage128x64(Bm, nBase, 1024, kt * 64, lB, lane, wave);
    __syncthreads();
    mfma_step(lA, lB, acc, lane, wm, wn);
    __syncthreads();
  }

  if (z < 2) {
    short* out = (z == 0) ? Q : K2;
#pragma unroll
    for (int i = 0; i < 4; ++i)
#pragma unroll
      for (int j = 0; j < 4; ++j) {
        int col = (int)nBase + wn * 64 + j * 16 + (lane & 15);
#pragma unroll
        for (int r = 0; r < 4; ++r) {
          long m = mBase + wm * 64 + i * 16 + (lane >> 4) * 4 + r;
          out[m * 1024 + col] = f2bf(acc[i][j][r]);
        }
      }
  } else {
    // V transposed write: in Vt[b][d][s], the 4 r-values are s-contiguous -> short4 store
    const long bb = mBase >> 11;
    const int sBase = (int)(mBase & 2047);
#pragma unroll
    for (int i = 0; i < 4; ++i) {
      int s0 = sBase + wm * 64 + i * 16 + ((lane >> 4) << 2);
#pragma unroll
      for (int j = 0; j < 4; ++j) {
        int col = (int)nBase + wn * 64 + j * 16 + (lane & 15);
        short4 o;
        o.x = f2bf(acc[i][j][0]); o.y = f2bf(acc[i][j][1]);
        o.z = f2bf(acc[i][j][2]); o.w = f2bf(acc[i][j][3]);
        *(short4*)(Vt + ((bb * 1024 + col) * 2048 + s0)) = o;
      }
    }
  }
}

// ---- stage 2: E = exp(Q K^T / 32) on causal block pairs; row sums into l ----
__global__ __launch_bounds__(256, 3) void scores_exp(const short* __restrict__ Q,
                                                     const short* __restrict__ Kk,
                                                     short* __restrict__ E, float* __restrict__ l) {
  __shared__ short lA[128 * 64], lB[128 * 64];
  const int lane = threadIdx.x & 63, wave = threadIdx.x >> 6;
  const int wm = wave >> 1, wn = wave & 1;
  const int b = blockIdx.y;
  int qt = 0, rem = blockIdx.x;
  while (rem > qt) { rem -= (qt + 1); ++qt; }
  const int kt = rem;

  const long rowQ = (long)b * 2048 + (long)qt * 128;
  const long rowK = (long)b * 2048 + (long)kt * 128;

  floatx4 acc[4][4];
  const floatx4 zero = {0.f, 0.f, 0.f, 0.f};
#pragma unroll
  for (int i = 0; i < 4; ++i)
#pragma unroll
    for (int j = 0; j < 4; ++j) acc[i][j] = zero;

  for (int it = 0; it < 16; ++it) {
    stage128x64(Q, rowQ, 1024, it * 64, lA, lane, wave);
    stage128x64(Kk, rowK, 1024, it * 64, lB, lane, wave);
    __syncthreads();
    mfma_step(lA, lB, acc, lane, wm, wn);
    __syncthreads();
  }

  short* Eb = E + (long)b * 2048 * 2048;
  float* lrow = l + (long)b * 2048;
#pragma unroll
  for (int i = 0; i < 4; ++i) {
#pragma unroll
    for (int r = 0; r < 4; ++r) {
      int ri = wm * 64 + i * 16 + (lane >> 4) * 4 + r;
      int qrow = qt * 128 + ri;
      float p = 0.f;
#pragma unroll
      for (int j = 0; j < 4; ++j) {
        int col = kt * 128 + wn * 64 + j * 16 + (lane & 15);
        float s = acc[i][j][r] * 0.03125f;  // 1/sqrt(1024)
        float e = (col <= qrow) ? __expf(s) : 0.0f;
        short eb = f2bf(e);
        Eb[(long)qrow * 2048 + col] = eb;
        p += bf2f(eb);
      }
      for (int m = 1; m < 16; m <<= 1) p += __shfl_xor(p, m, 64);
      if ((lane & 15) == 0) atomicAdd(&lrow[qrow], p);
    }
  }
}

// ---- stage 3: O = (E @ V) / l ----
// One qt per block, 512 blocks (2/CU resident), longest-first dispatch (LPT):
// qt = 15 - blockIdx.x so the 32-iter blocks start first and the tail is short.
__global__ __launch_bounds__(256, 3) void pv_gemm(const short* __restrict__ E,
                                                  const short* __restrict__ Vt,
                                                  const float* __restrict__ l,
                                                  float* __restrict__ out) {
  __shared__ short lA[128 * 64], lB[128 * 64];
  const int lane = threadIdx.x & 63, wave = threadIdx.x >> 6;
  const int wm = wave >> 1, wn = wave & 1;
  const int qt = 15 - blockIdx.x, dt = blockIdx.y, b = blockIdx.z;
  const short* Eb = E + (long)b * 2048 * 2048;
  const short* Vb = Vt + (long)b * 1024 * 2048;
  const float* lrow = l + (long)b * 2048;

  floatx4 acc[4][4];
  const floatx4 zero = {0.f, 0.f, 0.f, 0.f};
#pragma unroll
  for (int i = 0; i < 4; ++i)
#pragma unroll
    for (int j = 0; j < 4; ++j) acc[i][j] = zero;

  const int nIter = (qt + 1) * 2;
  for (int it = 0; it < nIter; ++it) {
    stage128x64(Eb, (long)qt * 128, 2048, it * 64, lA, lane, wave);
    stage128x64(Vb, (long)dt * 128, 2048, it * 64, lB, lane, wave);
    __syncthreads();
    mfma_step(lA, lB, acc, lane, wm, wn);
    __syncthreads();
  }

#pragma unroll
  for (int i = 0; i < 4; ++i) {
#pragma unroll
    for (int r = 0; r < 4; ++r) {
      int qrow = qt * 128 + wm * 64 + i * 16 + (lane >> 4) * 4 + r;
      float inv = 1.0f / lrow[qrow];
#pragma unroll
      for (int j = 0; j < 4; ++j) {
        int d = dt * 128 + wn * 64 + j * 16 + (lane & 15);
        out[((long)b * 2048 + qrow) * 1024 + d] = acc[i][j][r] * inv;
      }
    }
  }
}

extern "C" void kernel_launch(void* const* d_in, const int* in_sizes, int n_in,
                              void* d_out, int out_size, void* d_ws, size_t ws_size,
                              hipStream_t stream) {
  const float* X  = (const float*)d_in[0];
  const float* Wq = (const float*)d_in[1];
  const float* Wk = (const float*)d_in[2];
  const float* Wv = (const float*)d_in[3];

  char* ws = (char*)d_ws;
  // layout (bytes): Xb 16M | Wt 6M | Q 16M | K 16M | Vt 16M | E 32M | l 32K
  short* Xb = (short*)(ws);
  short* Wt = (short*)(ws + 16777216L);
  short* Q  = (short*)(ws + 23068672L);
  short* K2 = (short*)(ws + 39845888L);
  short* Vt = (short*)(ws + 56623104L);
  short* E  = (short*)(ws + 73400320L);
  float* l  = (float*)(ws + 106954752L);

  hipMemsetAsync(l, 0, 4 * 2048 * sizeof(float), stream);
  convert_x<<<2048, 256, 0, stream>>>(X, Xb, 8192L * 1024);
  transpose_w<<<dim3(32, 32, 3), dim3(32, 8), 0, stream>>>(Wq, Wk, Wv, Wt);
  gemm_qkv<<<dim3(64, 8, 3), 256, 0, stream>>>(Xb, Wt, Q, K2, Vt);
  scores_exp<<<dim3(136, 4), 256, 0, stream>>>(Q, K2, E, l);
  pv_gemm<<<dim3(16, 8, 4), 256, 0, stream>>>(E, Vt, l, (float*)d_out);
}

// Round 4
// 244.137 us; speedup vs baseline: 1.1202x; 1.0219x over previous
//
#include <hip/hip_runtime.h>

#define AS1 __attribute__((address_space(1)))
#define AS3 __attribute__((address_space(3)))

typedef __attribute__((ext_vector_type(8))) short short8;
typedef __attribute__((ext_vector_type(4))) float floatx4;

// ---- bf16 helpers (RNE; inputs are finite, no NaN/Inf handling needed) ----
__device__ __forceinline__ short f2bf(float f) {
  union { float f; unsigned u; } v; v.f = f;
  return (short)((v.u + 0x7fffu + ((v.u >> 16) & 1u)) >> 16);
}
__device__ __forceinline__ float bf2f(short s) {
  union { unsigned u; float f; } v; v.u = ((unsigned)(unsigned short)s) << 16;
  return v.f;
}

// ---- async global->LDS, 16B per lane (wave-uniform LDS base + lane*16) ----
__device__ __forceinline__ void gload_lds16(const void* g, void* l) {
  __builtin_amdgcn_global_load_lds((const AS1 unsigned*)g, (AS3 unsigned*)l, 16, 0, 0);
}

// Stage a 128x64 bf16 tile (rows rowBase..+127, cols kBase..+63) of row-major G
// (leading dim `ld` elements) into contiguous 128x64 LDS. 256 threads / 4 waves.
__device__ __forceinline__ void stage128x64(const short* __restrict__ G, long rowBase, long ld,
                                            int kBase, short* lds, int lane, int wave) {
  const short* gb = G + rowBase * ld + (long)kBase + (long)(lane >> 3) * ld + (lane & 7) * 8;
#pragma unroll
  for (int j = 0; j < 4; ++j) {
    int c = wave * 4 + j;
    gload_lds16(gb + (long)c * 8 * ld, lds + c * 512);
  }
}

// One BK=64 step of 128x128 MFMA tile compute. Wave (wm,wn) owns a 64x64 C block.
__device__ __forceinline__ void mfma_step(const short* lA, const short* lB, floatx4 acc[4][4],
                                          int lane, int wm, int wn) {
#pragma unroll
  for (int kk = 0; kk < 64; kk += 32) {
    short8 a[4], b[4];
    int kq = kk + (lane >> 4) * 8;
#pragma unroll
    for (int i = 0; i < 4; ++i) {
      a[i] = *(const short8*)(lA + (wm * 64 + i * 16 + (lane & 15)) * 64 + kq);
      b[i] = *(const short8*)(lB + (wn * 64 + i * 16 + (lane & 15)) * 64 + kq);
    }
#pragma unroll
    for (int i = 0; i < 4; ++i)
#pragma unroll
      for (int j = 0; j < 4; ++j)
        acc[i][j] = __builtin_amdgcn_mfma_f32_16x16x32_bf16(a[i], b[j], acc[i][j], 0, 0, 0);
  }
}

// ---- stage 0 (fused): blocks [0,8192) convert X fp32->bf16; [8192,11264) transpose W ----
__global__ void prep_inputs(const float* __restrict__ X, const float* __restrict__ Wq,
                            const float* __restrict__ Wk, const float* __restrict__ Wv,
                            short* __restrict__ Xb, short* __restrict__ Wt) {
  __shared__ float t[32][33];
  if (blockIdx.x < 8192) {
    long i = ((long)blockIdx.x * 256 + threadIdx.x) * 4;
    float4 v = *(const float4*)(X + i);
    short4 o;
    o.x = f2bf(v.x); o.y = f2bf(v.y); o.z = f2bf(v.z); o.w = f2bf(v.w);
    *(short4*)(Xb + i) = o;
  } else {
    int idx = blockIdx.x - 8192;           // [0,3072): z*1024 + bx*32 + by
    int z = idx >> 10, rem = idx & 1023;
    int bx = rem >> 5, by = rem & 31;
    const float* W = z == 0 ? Wq : (z == 1 ? Wk : Wv);
    short* O = Wt + (long)z * 1024 * 1024;
    int tx = threadIdx.x & 31, ty = threadIdx.x >> 5;
    int x = bx * 32 + tx;
    int y0 = by * 32;
    for (int j = ty; j < 32; j += 8)
      t[j][tx] = W[(long)(y0 + j) * 1024 + x];
    __syncthreads();
    int x2 = by * 32 + tx;
    int y2 = bx * 32;
    for (int j = ty; j < 32; j += 8)
      O[(long)(y2 + j) * 1024 + x2] = f2bf(t[tx][j]);
  }
}

// ---- stage 1: Q/K/V = X @ W ----
// z=0 -> Q [8192,1024], z=1 -> K [8192,1024], z=2 -> Vt [b][d][s]
__global__ __launch_bounds__(256, 3) void gemm_qkv(const short* __restrict__ Xb,
                                                   const short* __restrict__ Wt,
                                                   short* __restrict__ Q, short* __restrict__ K2,
                                                   short* __restrict__ Vt) {
  __shared__ short lA[128 * 64], lB[128 * 64];
  const int lane = threadIdx.x & 63, wave = threadIdx.x >> 6;
  const int wm = wave >> 1, wn = wave & 1;
  const int z = blockIdx.z;
  const short* Bm = Wt + (long)z * 1024 * 1024;
  const long mBase = (long)blockIdx.x * 128;
  const long nBase = (long)blockIdx.y * 128;

  floatx4 acc[4][4];
  const floatx4 zero = {0.f, 0.f, 0.f, 0.f};
#pragma unroll
  for (int i = 0; i < 4; ++i)
#pragma unroll
    for (int j = 0; j < 4; ++j) acc[i][j] = zero;

  for (int kt = 0; kt < 16; ++kt) {
    stage128x64(Xb, mBase, 1024, kt * 64, lA, lane, wave);
    stage128x64(Bm, nBase, 1024, kt * 64, lB, lane, wave);
    __syncthreads();
    mfma_step(lA, lB, acc, lane, wm, wn);
    __syncthreads();
  }

  if (z < 2) {
    short* out = (z == 0) ? Q : K2;
#pragma unroll
    for (int i = 0; i < 4; ++i)
#pragma unroll
      for (int j = 0; j < 4; ++j) {
        int col = (int)nBase + wn * 64 + j * 16 + (lane & 15);
#pragma unroll
        for (int r = 0; r < 4; ++r) {
          long m = mBase + wm * 64 + i * 16 + (lane >> 4) * 4 + r;
          out[m * 1024 + col] = f2bf(acc[i][j][r]);
        }
      }
  } else {
    // V transposed write: in Vt[b][d][s], the 4 r-values are s-contiguous -> short4 store
    const long bb = mBase >> 11;
    const int sBase = (int)(mBase & 2047);
#pragma unroll
    for (int i = 0; i < 4; ++i) {
      int s0 = sBase + wm * 64 + i * 16 + ((lane >> 4) << 2);
#pragma unroll
      for (int j = 0; j < 4; ++j) {
        int col = (int)nBase + wn * 64 + j * 16 + (lane & 15);
        short4 o;
        o.x = f2bf(acc[i][j][0]); o.y = f2bf(acc[i][j][1]);
        o.z = f2bf(acc[i][j][2]); o.w = f2bf(acc[i][j][3]);
        *(short4*)(Vt + ((bb * 1024 + col) * 2048 + s0)) = o;
      }
    }
  }
}

// ---- stage 2: E = exp(Q K^T / 32) on causal block pairs; row sums into l ----
__global__ __launch_bounds__(256, 3) void scores_exp(const short* __restrict__ Q,
                                                     const short* __restrict__ Kk,
                                                     short* __restrict__ E, float* __restrict__ l) {
  __shared__ short lA[128 * 64], lB[128 * 64];
  const int lane = threadIdx.x & 63, wave = threadIdx.x >> 6;
  const int wm = wave >> 1, wn = wave & 1;
  const int b = blockIdx.y;
  int qt = 0, rem = blockIdx.x;
  while (rem > qt) { rem -= (qt + 1); ++qt; }
  const int kt = rem;

  const long rowQ = (long)b * 2048 + (long)qt * 128;
  const long rowK = (long)b * 2048 + (long)kt * 128;

  floatx4 acc[4][4];
  const floatx4 zero = {0.f, 0.f, 0.f, 0.f};
#pragma unroll
  for (int i = 0; i < 4; ++i)
#pragma unroll
    for (int j = 0; j < 4; ++j) acc[i][j] = zero;

  for (int it = 0; it < 16; ++it) {
    stage128x64(Q, rowQ, 1024, it * 64, lA, lane, wave);
    stage128x64(Kk, rowK, 1024, it * 64, lB, lane, wave);
    __syncthreads();
    mfma_step(lA, lB, acc, lane, wm, wn);
    __syncthreads();
  }

  short* Eb = E + (long)b * 2048 * 2048;
  float* lrow = l + (long)b * 2048;
#pragma unroll
  for (int i = 0; i < 4; ++i) {
#pragma unroll
    for (int r = 0; r < 4; ++r) {
      int ri = wm * 64 + i * 16 + (lane >> 4) * 4 + r;
      int qrow = qt * 128 + ri;
      float p = 0.f;
#pragma unroll
      for (int j = 0; j < 4; ++j) {
        int col = kt * 128 + wn * 64 + j * 16 + (lane & 15);
        float s = acc[i][j][r] * 0.03125f;  // 1/sqrt(1024)
        float e = (col <= qrow) ? __expf(s) : 0.0f;
        short eb = f2bf(e);
        Eb[(long)qrow * 2048 + col] = eb;
        p += bf2f(eb);
      }
      for (int m = 1; m < 16; m <<= 1) p += __shfl_xor(p, m, 64);
      if ((lane & 15) == 0) atomicAdd(&lrow[qrow], p);
    }
  }
}

// ---- stage 3: O = (E @ V) / l, split-K to cap the sequential chain at 16 iters ----
// Grid x in [0,24): x<16 -> split pair for qt = 8+(x>>1), chunk = x&1
//                   x>=16 -> direct qt = x-16 (0..7)
// Split: chunk0 stores raw fp32 sums to out; chunk1 stores raw sums to `part`
// (the dead Xb region); pv_reduce then computes (out+part)/l for rows qt>=8.
// 768 blocks = exactly 3/CU: all co-resident, max chain 16 iters.
__global__ __launch_bounds__(256, 3) void pv_gemm(const short* __restrict__ E,
                                                  const short* __restrict__ Vt,
                                                  const float* __restrict__ l,
                                                  float* __restrict__ part,
                                                  float* __restrict__ out) {
  __shared__ short lA[128 * 64], lB[128 * 64];
  const int lane = threadIdx.x & 63, wave = threadIdx.x >> 6;
  const int wm = wave >> 1, wn = wave & 1;
  const int x = blockIdx.x, dt = blockIdx.y, b = blockIdx.z;

  int qt, it0, it1, mode;  // mode: 0 direct(/l), 1 chunk0->out raw, 2 chunk1->part raw
  if (x < 16) {
    qt = 8 + (x >> 1);
    const int T = (qt + 1) * 2, c0 = T >> 1;
    if ((x & 1) == 0) { it0 = 0; it1 = c0; mode = 1; }
    else              { it0 = c0; it1 = T; mode = 2; }
  } else {
    qt = x - 16; it0 = 0; it1 = (qt + 1) * 2; mode = 0;
  }

  const short* Eb = E + (long)b * 2048 * 2048;
  const short* Vb = Vt + (long)b * 1024 * 2048;
  const float* lrow = l + (long)b * 2048;

  floatx4 acc[4][4];
  const floatx4 zero = {0.f, 0.f, 0.f, 0.f};
#pragma unroll
  for (int i = 0; i < 4; ++i)
#pragma unroll
    for (int j = 0; j < 4; ++j) acc[i][j] = zero;

  for (int it = it0; it < it1; ++it) {
    stage128x64(Eb, (long)qt * 128, 2048, it * 64, lA, lane, wave);
    stage128x64(Vb, (long)dt * 128, 2048, it * 64, lB, lane, wave);
    __syncthreads();
    mfma_step(lA, lB, acc, lane, wm, wn);
    __syncthreads();
  }

  if (mode == 2) {
    // partial tile index: ((b*8 + qt-8)*8 + dt) -> 128x128 fp32
    float* P = part + ((((long)b * 8 + (qt - 8)) * 8 + dt) << 14);
#pragma unroll
    for (int i = 0; i < 4; ++i)
#pragma unroll
      for (int r = 0; r < 4; ++r) {
        int ri = wm * 64 + i * 16 + (lane >> 4) * 4 + r;
#pragma unroll
        for (int j = 0; j < 4; ++j) {
          int ci = wn * 64 + j * 16 + (lane & 15);
          P[ri * 128 + ci] = acc[i][j][r];
        }
      }
  } else {
#pragma unroll
    for (int i = 0; i < 4; ++i)
#pragma unroll
      for (int r = 0; r < 4; ++r) {
        int qrow = qt * 128 + wm * 64 + i * 16 + (lane >> 4) * 4 + r;
        float scale = (mode == 0) ? 1.0f / lrow[qrow] : 1.0f;
#pragma unroll
        for (int j = 0; j < 4; ++j) {
          int d = dt * 128 + wn * 64 + j * 16 + (lane & 15);
          out[((long)b * 2048 + qrow) * 1024 + d] = acc[i][j][r] * scale;
        }
      }
  }
}

// ---- stage 4: rows qt>=8: out = (out + part)/l ----
__global__ void pv_reduce(float* __restrict__ out, const float* __restrict__ part,
                          const float* __restrict__ l) {
  const int idx = blockIdx.x;           // 4096 = 4b * 1024 rows
  const int b = idx >> 10;
  const int row = 1024 + (idx & 1023);  // global row in [1024, 2048)
  const int t = threadIdx.x;
  const int dt = t >> 5, dl = (t << 2) & 127;
  const float inv = 1.0f / l[((long)b << 11) + row];
  const long pbase = ((((long)b * 8 + ((row >> 7) - 8)) * 8 + dt) << 14) + ((row & 127) << 7) + dl;
  const long obase = (((long)b * 2048 + row) << 10) + (t << 2);
  float4 o = *(const float4*)(out + obase);
  float4 p = *(const float4*)(part + pbase);
  o.x = (o.x + p.x) * inv; o.y = (o.y + p.y) * inv;
  o.z = (o.z + p.z) * inv; o.w = (o.w + p.w) * inv;
  *(float4*)(out + obase) = o;
}

extern "C" void kernel_launch(void* const* d_in, const int* in_sizes, int n_in,
                              void* d_out, int out_size, void* d_ws, size_t ws_size,
                              hipStream_t stream) {
  const float* X  = (const float*)d_in[0];
  const float* Wq = (const float*)d_in[1];
  const float* Wk = (const float*)d_in[2];
  const float* Wv = (const float*)d_in[3];

  char* ws = (char*)d_ws;
  // layout (bytes): Xb 16M (reused as pv partials) | Wt 6M | Q 16M | K 16M | Vt 16M | E 32M | l 32K
  short* Xb = (short*)(ws);
  short* Wt = (short*)(ws + 16777216L);
  short* Q  = (short*)(ws + 23068672L);
  short* K2 = (short*)(ws + 39845888L);
  short* Vt = (short*)(ws + 56623104L);
  short* E  = (short*)(ws + 73400320L);
  float* l  = (float*)(ws + 106954752L);
  float* part = (float*)(ws);  // 256 tiles * 64KB = 16MB, overlays dead Xb

  hipMemsetAsync(l, 0, 4 * 2048 * sizeof(float), stream);
  prep_inputs<<<11264, 256, 0, stream>>>(X, Wq, Wk, Wv, Xb, Wt);
  gemm_qkv<<<dim3(64, 8, 3), 256, 0, stream>>>(Xb, Wt, Q, K2, Vt);
  scores_exp<<<dim3(136, 4), 256, 0, stream>>>(Q, K2, E, l);
  pv_gemm<<<dim3(24, 8, 4), 256, 0, stream>>>(E, Vt, l, part, (float*)d_out);
  pv_reduce<<<4096, 256, 0, stream>>>((float*)d_out, part, l);
}

// Round 6
// 238.949 us; speedup vs baseline: 1.1445x; 1.0217x over previous
//
#include <hip/hip_runtime.h>

#define AS1 __attribute__((address_space(1)))
#define AS3 __attribute__((address_space(3)))

typedef __attribute__((ext_vector_type(8))) short short8;
typedef __attribute__((ext_vector_type(4))) float floatx4;

// ---- bf16 helpers (RNE; inputs are finite, no NaN/Inf handling needed) ----
__device__ __forceinline__ short f2bf(float f) {
  union { float f; unsigned u; } v; v.f = f;
  return (short)((v.u + 0x7fffu + ((v.u >> 16) & 1u)) >> 16);
}
__device__ __forceinline__ float bf2f(short s) {
  union { unsigned u; float f; } v; v.u = ((unsigned)(unsigned short)s) << 16;
  return v.f;
}

// ---- async global->LDS, 16B per lane (wave-uniform LDS base + lane*16) ----
__device__ __forceinline__ void gload_lds16(const void* g, void* l) {
  __builtin_amdgcn_global_load_lds((const AS1 unsigned*)g, (AS3 unsigned*)l, 16, 0, 0);
}

// Stage a 128x64 bf16 tile (rows rowBase..+127, cols kBase..+63) of row-major G
// (leading dim `ld` elements) into contiguous 128x64 LDS. 256 threads / 4 waves.
__device__ __forceinline__ void stage128x64(const short* __restrict__ G, long rowBase, long ld,
                                            int kBase, short* lds, int lane, int wave) {
  const short* gb = G + rowBase * ld + (long)kBase + (long)(lane >> 3) * ld + (lane & 7) * 8;
#pragma unroll
  for (int j = 0; j < 4; ++j) {
    int c = wave * 4 + j;
    gload_lds16(gb + (long)c * 8 * ld, lds + c * 512);
  }
}

// One BK=64 step of 128x128 MFMA tile compute. Wave (wm,wn) owns a 64x64 C block.
__device__ __forceinline__ void mfma_step(const short* lA, const short* lB, floatx4 acc[4][4],
                                          int lane, int wm, int wn) {
#pragma unroll
  for (int kk = 0; kk < 64; kk += 32) {
    short8 a[4], b[4];
    int kq = kk + (lane >> 4) * 8;
#pragma unroll
    for (int i = 0; i < 4; ++i) {
      a[i] = *(const short8*)(lA + (wm * 64 + i * 16 + (lane & 15)) * 64 + kq);
      b[i] = *(const short8*)(lB + (wn * 64 + i * 16 + (lane & 15)) * 64 + kq);
    }
#pragma unroll
    for (int i = 0; i < 4; ++i)
#pragma unroll
      for (int j = 0; j < 4; ++j)
        acc[i][j] = __builtin_amdgcn_mfma_f32_16x16x32_bf16(a[i], b[j], acc[i][j], 0, 0, 0);
  }
}

// ---- stage 0 (fused): blocks [0,8192) convert X fp32->bf16; [8192,11264) transpose W ----
__global__ void prep_inputs(const float* __restrict__ X, const float* __restrict__ Wq,
                            const float* __restrict__ Wk, const float* __restrict__ Wv,
                            short* __restrict__ Xb, short* __restrict__ Wt) {
  __shared__ float t[32][33];
  if (blockIdx.x < 8192) {
    long i = ((long)blockIdx.x * 256 + threadIdx.x) * 4;
    float4 v = *(const float4*)(X + i);
    short4 o;
    o.x = f2bf(v.x); o.y = f2bf(v.y); o.z = f2bf(v.z); o.w = f2bf(v.w);
    *(short4*)(Xb + i) = o;
  } else {
    int idx = blockIdx.x - 8192;           // [0,3072): z*1024 + bx*32 + by
    int z = idx >> 10, rem = idx & 1023;
    int bx = rem >> 5, by = rem & 31;
    const float* W = z == 0 ? Wq : (z == 1 ? Wk : Wv);
    short* O = Wt + (long)z * 1024 * 1024;
    int tx = threadIdx.x & 31, ty = threadIdx.x >> 5;
    int x = bx * 32 + tx;
    int y0 = by * 32;
    for (int j = ty; j < 32; j += 8)
      t[j][tx] = W[(long)(y0 + j) * 1024 + x];
    __syncthreads();
    int x2 = by * 32 + tx;
    int y2 = bx * 32;
    for (int j = ty; j < 32; j += 8)
      O[(long)(y2 + j) * 1024 + x2] = f2bf(t[tx][j]);
  }
}

// ---- stage 1: Q/K/V = X @ W ----
// z=0 -> Q [8192,1024], z=1 -> K [8192,1024], z=2 -> Vt [b][d][s]
__global__ __launch_bounds__(256, 3) void gemm_qkv(const short* __restrict__ Xb,
                                                   const short* __restrict__ Wt,
                                                   short* __restrict__ Q, short* __restrict__ K2,
                                                   short* __restrict__ Vt) {
  __shared__ short lA[128 * 64], lB[128 * 64];
  const int lane = threadIdx.x & 63, wave = threadIdx.x >> 6;
  const int wm = wave >> 1, wn = wave & 1;
  const int z = blockIdx.z;
  const short* Bm = Wt + (long)z * 1024 * 1024;
  const long mBase = (long)blockIdx.x * 128;
  const long nBase = (long)blockIdx.y * 128;

  floatx4 acc[4][4];
  const floatx4 zero = {0.f, 0.f, 0.f, 0.f};
#pragma unroll
  for (int i = 0; i < 4; ++i)
#pragma unroll
    for (int j = 0; j < 4; ++j) acc[i][j] = zero;

  for (int kt = 0; kt < 16; ++kt) {
    stage128x64(Xb, mBase, 1024, kt * 64, lA, lane, wave);
    stage128x64(Bm, nBase, 1024, kt * 64, lB, lane, wave);
    __syncthreads();
    mfma_step(lA, lB, acc, lane, wm, wn);
    __syncthreads();
  }

  if (z < 2) {
    short* out = (z == 0) ? Q : K2;
#pragma unroll
    for (int i = 0; i < 4; ++i)
#pragma unroll
      for (int j = 0; j < 4; ++j) {
        int col = (int)nBase + wn * 64 + j * 16 + (lane & 15);
#pragma unroll
        for (int r = 0; r < 4; ++r) {
          long m = mBase + wm * 64 + i * 16 + (lane >> 4) * 4 + r;
          out[m * 1024 + col] = f2bf(acc[i][j][r]);
        }
      }
  } else {
    // V transposed write: in Vt[b][d][s], the 4 r-values are s-contiguous -> short4 store
    const long bb = mBase >> 11;
    const int sBase = (int)(mBase & 2047);
#pragma unroll
    for (int i = 0; i < 4; ++i) {
      int s0 = sBase + wm * 64 + i * 16 + ((lane >> 4) << 2);
#pragma unroll
      for (int j = 0; j < 4; ++j) {
        int col = (int)nBase + wn * 64 + j * 16 + (lane & 15);
        short4 o;
        o.x = f2bf(acc[i][j][0]); o.y = f2bf(acc[i][j][1]);
        o.z = f2bf(acc[i][j][2]); o.w = f2bf(acc[i][j][3]);
        *(short4*)(Vt + ((bb * 1024 + col) * 2048 + s0)) = o;
      }
    }
  }
}

// ---- stage 2: E = exp(Q K^T / 32) on causal block pairs; row sums into l ----
// XCD-locality supertile schedule: 4x4 supertiles of (qt,kt) pairs.
// Residue r = blockIdx.x%8 selects the XCD class; classes 0-5 get one off-diag
// supertile (16 pairs: s in {1,3,4,6,7,8}), classes 6,7 get two diagonal
// supertiles (10+10 pairs). Blocks of a class share 8 (or 4) Q/K row-tiles.
__global__ __launch_bounds__(256, 3) void scores_exp(const short* __restrict__ Q,
                                                     const short* __restrict__ Kk,
                                                     short* __restrict__ E, float* __restrict__ l) {
  __shared__ short lbuf[16384];  // lA=lbuf[0:8192), lB=lbuf[8192:16384); epilogue: 128x128 E tile
  short* lA = lbuf;
  short* lB = lbuf + 8192;
  const int lane = threadIdx.x & 63, wave = threadIdx.x >> 6;
  const int wm = wave >> 1, wn = wave & 1;
  const int b = blockIdx.y;

  // decode (qt,kt) from supertile schedule
  const int r = blockIdx.x & 7, w = blockIdx.x >> 3;
  int s, p;
  if (r < 6) {
    if (w >= 16) return;
    s = (r == 5) ? 8 : r + 1 + ((r + 1) >> 1);  // {1,3,4,6,7,8}
    p = w;
  } else {
    if (w >= 20) return;
    if (r == 6) s = (w < 10) ? 0 : 2;   // (0,0), (1,1)
    else        s = (w < 10) ? 5 : 9;   // (2,2), (3,3)
    p = (w < 10) ? w : w - 10;
  }
  const int QT = (s >= 1) + (s >= 3) + (s >= 6);
  const int KT = s - (QT * (QT + 1)) / 2;
  int dq, dk;
  if (QT > KT) { dq = p >> 2; dk = p & 3; }
  else {
    dq = 0;
    while ((dq + 1) * (dq + 2) / 2 <= p) ++dq;
    dk = p - (dq * (dq + 1)) / 2;
  }
  const int qt = QT * 4 + dq, kt = KT * 4 + dk;

  const long rowQ = (long)b * 2048 + (long)qt * 128;
  const long rowK = (long)b * 2048 + (long)kt * 128;

  floatx4 acc[4][4];
  const floatx4 zero = {0.f, 0.f, 0.f, 0.f};
#pragma unroll
  for (int i = 0; i < 4; ++i)
#pragma unroll
    for (int j = 0; j < 4; ++j) acc[i][j] = zero;

  for (int it = 0; it < 16; ++it) {
    stage128x64(Q, rowQ, 1024, it * 64, lA, lane, wave);
    stage128x64(Kk, rowK, 1024, it * 64, lB, lane, wave);
    __syncthreads();
    mfma_step(lA, lB, acc, lane, wm, wn);
    __syncthreads();
  }
  // last loop iter ended with __syncthreads(): lbuf is free for the epilogue tile.

  float* lrow = l + (long)b * 2048;
  // exp + write E tile into LDS (16B-chunk XOR swizzle to dodge bank conflicts) + row sums
#pragma unroll
  for (int i = 0; i < 4; ++i) {
#pragma unroll
    for (int rr = 0; rr < 4; ++rr) {
      int ri = wm * 64 + i * 16 + (lane >> 4) * 4 + rr;
      int qrow = qt * 128 + ri;
      float psum = 0.f;
#pragma unroll
      for (int j = 0; j < 4; ++j) {
        int ci = wn * 64 + j * 16 + (lane & 15);
        int col = kt * 128 + ci;
        float sc = acc[i][j][rr] * 0.03125f;  // 1/sqrt(1024)
        float e = (col <= qrow) ? __expf(sc) : 0.0f;
        short eb = f2bf(e);
        lbuf[ri * 128 + ((((ci >> 3) ^ (ri & 15)) << 3) | (ci & 7))] = eb;
        psum += bf2f(eb);
      }
      for (int m = 1; m < 16; m <<= 1) psum += __shfl_xor(psum, m, 64);
      if ((lane & 15) == 0) atomicAdd(&lrow[qrow], psum);
    }
  }
  __syncthreads();

  // coalesced 16B stores: 2048 chunks, 8 per thread
  short* Eb = E + (long)b * 4194304;
  const long ebase = (long)(qt * 128) * 2048 + kt * 128;
#pragma unroll
  for (int pp = 0; pp < 8; ++pp) {
    int g = pp * 256 + threadIdx.x;
    int row = g >> 4, c = g & 15;
    short8 v = *(const short8*)(lbuf + row * 128 + ((c ^ (row & 15)) << 3));
    *(short8*)(Eb + ebase + (long)row * 2048 + c * 8) = v;
  }
}

// ---- stage 3: O = (E @ V) / l, split-K + XCD-locality swizzle ----
// x = dt*24 + (w*8 + r): all k-slots of residue r land on XCD r; for each (b,dt)
// residue r owns {qt=15-r chunk0, qt=15-r chunk1, qt=r direct} = exactly 34 iters
// (perfectly balanced), and E[qt] rows live in that XCD's L2 (~2.3MB < 4MB).
__global__ __launch_bounds__(256, 3) void pv_gemm(const short* __restrict__ E,
                                                  const short* __restrict__ Vt,
                                                  const float* __restrict__ l,
                                                  float* __restrict__ part,
                                                  float* __restrict__ out) {
  __shared__ short lA[128 * 64], lB[128 * 64];
  const int lane = threadIdx.x & 63, wave = threadIdx.x >> 6;
  const int wm = wave >> 1, wn = wave & 1;
  const int xx = blockIdx.x;            // [0,192)
  const int dt = xx / 24;
  const int within = xx % 24;
  const int r = within & 7, wsel = within >> 3;  // wsel in {0,1,2}
  const int b = blockIdx.y;

  int qt, it0, it1, mode;  // mode: 0 direct(/l), 1 chunk0->out raw, 2 chunk1->part raw
  if (wsel == 2) {
    qt = r; it0 = 0; it1 = (qt + 1) * 2; mode = 0;
  } else {
    qt = 15 - r;
    const int T = (qt + 1) * 2, c0 = T >> 1;
    if (wsel == 0) { it0 = 0;  it1 = c0; mode = 1; }
    else           { it0 = c0; it1 = T;  mode = 2; }
  }

  const short* Eb = E + (long)b * 2048 * 2048;
  const short* Vb = Vt + (long)b * 1024 * 2048;
  const float* lrow = l + (long)b * 2048;

  floatx4 acc[4][4];
  const floatx4 zero = {0.f, 0.f, 0.f, 0.f};
#pragma unroll
  for (int i = 0; i < 4; ++i)
#pragma unroll
    for (int j = 0; j < 4; ++j) acc[i][j] = zero;

  for (int it = it0; it < it1; ++it) {
    stage128x64(Eb, (long)qt * 128, 2048, it * 64, lA, lane, wave);
    stage128x64(Vb, (long)dt * 128, 2048, it * 64, lB, lane, wave);
    __syncthreads();
    mfma_step(lA, lB, acc, lane, wm, wn);
    __syncthreads();
  }

  if (mode == 2) {
    // partial tile index: ((b*8 + qt-8)*8 + dt) -> 128x128 fp32
    float* P = part + ((((long)b * 8 + (qt - 8)) * 8 + dt) << 14);
#pragma unroll
    for (int i = 0; i < 4; ++i)
#pragma unroll
      for (int rr = 0; rr < 4; ++rr) {
        int ri = wm * 64 + i * 16 + (lane >> 4) * 4 + rr;
#pragma unroll
        for (int j = 0; j < 4; ++j) {
          int ci = wn * 64 + j * 16 + (lane & 15);
          P[ri * 128 + ci] = acc[i][j][rr];
        }
      }
  } else {
#pragma unroll
    for (int i = 0; i < 4; ++i)
#pragma unroll
      for (int rr = 0; rr < 4; ++rr) {
        int qrow = qt * 128 + wm * 64 + i * 16 + (lane >> 4) * 4 + rr;
        float scale = (mode == 0) ? 1.0f / lrow[qrow] : 1.0f;
#pragma unroll
        for (int j = 0; j < 4; ++j) {
          int d = dt * 128 + wn * 64 + j * 16 + (lane & 15);
          out[((long)b * 2048 + qrow) * 1024 + d] = acc[i][j][rr] * scale;
        }
      }
  }
}

// ---- stage 4: rows qt>=8: out = (out + part)/l ----
__global__ void pv_reduce(float* __restrict__ out, const float* __restrict__ part,
                          const float* __restrict__ l) {
  const int idx = blockIdx.x;           // 4096 = 4b * 1024 rows
  const int b = idx >> 10;
  const int row = 1024 + (idx & 1023);  // global row in [1024, 2048)
  const int t = threadIdx.x;
  const int dt = t >> 5, dl = (t << 2) & 127;
  const float inv = 1.0f / l[((long)b << 11) + row];
  const long pbase = ((((long)b * 8 + ((row >> 7) - 8)) * 8 + dt) << 14) + ((row & 127) << 7) + dl;
  const long obase = (((long)b * 2048 + row) << 10) + (t << 2);
  float4 o = *(const float4*)(out + obase);
  float4 p = *(const float4*)(part + pbase);
  o.x = (o.x + p.x) * inv; o.y = (o.y + p.y) * inv;
  o.z = (o.z + p.z) * inv; o.w = (o.w + p.w) * inv;
  *(float4*)(out + obase) = o;
}

extern "C" void kernel_launch(void* const* d_in, const int* in_sizes, int n_in,
                              void* d_out, int out_size, void* d_ws, size_t ws_size,
                              hipStream_t stream) {
  const float* X  = (const float*)d_in[0];
  const float* Wq = (const float*)d_in[1];
  const float* Wk = (const float*)d_in[2];
  const float* Wv = (const float*)d_in[3];

  char* ws = (char*)d_ws;
  // layout (bytes): Xb 16M (reused as pv partials) | Wt 6M | Q 16M | K 16M | Vt 16M | E 32M | l 32K
  short* Xb = (short*)(ws);
  short* Wt = (short*)(ws + 16777216L);
  short* Q  = (short*)(ws + 23068672L);
  short* K2 = (short*)(ws + 39845888L);
  short* Vt = (short*)(ws + 56623104L);
  short* E  = (short*)(ws + 73400320L);
  float* l  = (float*)(ws + 106954752L);
  float* part = (float*)(ws);  // 256 tiles * 64KB = 16MB, overlays dead Xb

  hipMemsetAsync(l, 0, 4 * 2048 * sizeof(float), stream);
  prep_inputs<<<11264, 256, 0, stream>>>(X, Wq, Wk, Wv, Xb, Wt);
  gemm_qkv<<<dim3(64, 8, 3), 256, 0, stream>>>(Xb, Wt, Q, K2, Vt);
  scores_exp<<<dim3(160, 4), 256, 0, stream>>>(Q, K2, E, l);
  pv_gemm<<<dim3(192, 4), 256, 0, stream>>>(E, Vt, l, part, (float*)d_out);
  pv_reduce<<<4096, 256, 0, stream>>>((float*)d_out, part, l);
}